// Round 13
// baseline (343.782 us; speedup 1.0000x reference)
//
#include <hip/hip_runtime.h>
#include <cstdint>
#include <cstddef>

#define H 1024
#define NB 8
#define S 2048
#define MROWS (NB*S)

using short8  = __attribute__((ext_vector_type(8))) short;
using ushort8 = __attribute__((ext_vector_type(8))) unsigned short;
using f32x4   = __attribute__((ext_vector_type(4))) float;

__device__ __forceinline__ unsigned short f2bf(float f){
  union { float f; unsigned int u; } c; c.f = f;
  unsigned int u = c.u;
  return (unsigned short)((u + 0x7fffu + ((u >> 16) & 1u)) >> 16);
}
__device__ __forceinline__ float bf2f(unsigned short b){
  union { unsigned int u; float f; } c; c.u = ((unsigned int)b) << 16;
  return c.f;
}

// ---------------- merged prep kernel ----------------
// blocks [0,3072): W cvt f32->bf16 ; [3072,3136): colproj partials ;
// [3136,3648): ctxproj ; 3648: scalar dots
__global__ __launch_bounds__(256) void k_prep(
    const float* __restrict__ Wq, const float* __restrict__ Wk, const float* __restrict__ Wv,
    const float* __restrict__ Wcq, const float* __restrict__ Wck, const float* __restrict__ ctx,
    const float* __restrict__ gqh, const float* __restrict__ gkh,
    const float* __restrict__ bq, const float* __restrict__ bk,
    const float* __restrict__ gqc, const float* __restrict__ gkc,
    unsigned short* __restrict__ wqb, unsigned short* __restrict__ wkb, unsigned short* __restrict__ wvb,
    float* __restrict__ up, float* __restrict__ ctxq, float* __restrict__ ctxk,
    float* __restrict__ scal)
{
  __shared__ float cs[NB * H];
  const int bid = blockIdx.x;
  const int t = threadIdx.x;
  if (bid < 3072){
    const int y = bid >> 10;
    const int x = bid & 1023;
    const float* src = y == 0 ? Wq : (y == 1 ? Wk : Wv);
    unsigned short* dst = y == 0 ? wqb : (y == 1 ? wkb : wvb);
    const int i = (x * 256 + t) * 4;
    float4 v = *reinterpret_cast<const float4*>(src + i);
    ushort4 o; o.x = f2bf(v.x); o.y = f2bf(v.y); o.z = f2bf(v.z); o.w = f2bf(v.w);
    *reinterpret_cast<ushort4*>(dst + i) = o;
  } else if (bid < 3136){
    const int sub = bid - 3072;
    const int z = sub >> 5;          // 0..1
    const int y = (sub >> 2) & 7;    // 0..7
    const int x = sub & 3;           // 0..3
    const float* W = z ? Wk : Wq;
    const float* g = z ? gkh : gqh;
    const int in = x * 256 + t;
    const int o0 = y * 128;
    float s = 0.f;
    for (int o = 0; o < 128; ++o) s = fmaf(W[(size_t)(o0 + o) * H + in], g[o0 + o], s);
    up[(z * 8 + y) * 1024 + in] = s;
  } else if (bid < 3648){
    const int sub = bid - 3136;
    const int y = sub >> 8;          // 0..1
    const int x = sub & 255;
    const float* W = y ? Wck : Wcq;
    float* out = y ? ctxk : ctxq;
    for (int i = t; i < NB * H; i += 256) cs[i] = ctx[i];
    __syncthreads();
    const int wid = t >> 6, lane = t & 63;
    const int row = x * 4 + wid;
    float a[NB];
    #pragma unroll
    for (int b = 0; b < NB; ++b) a[b] = 0.f;
    for (int i0 = 0; i0 < H; i0 += 64){
      const float w = W[(size_t)row * H + i0 + lane];
      #pragma unroll
      for (int b = 0; b < NB; ++b) a[b] = fmaf(w, cs[b * H + i0 + lane], a[b]);
    }
    #pragma unroll
    for (int b = 0; b < NB; ++b){
      float v = a[b];
      #pragma unroll
      for (int off = 32; off > 0; off >>= 1) v += __shfl_xor(v, off);
      if (lane == 0) out[b * H + row] = v;
    }
  } else {
    // 18 scalar dots, 4 waves
    const int wid = t >> 6, lane = t & 63;
    for (int d = wid; d < 18; d += 4){
      const float *pa, *pb;
      if (d == 0){ pa = bq; pb = gqh; }
      else if (d == 1){ pa = bk; pb = gkh; }
      else if (d < 10){ pa = ctx + (d - 2) * H; pb = gqc; }
      else { pa = ctx + (d - 10) * H; pb = gkc; }
      float s = 0.f;
      for (int i = lane; i < H; i += 64) s = fmaf(pa[i], pb[i], s);
      #pragma unroll
      for (int off = 32; off > 0; off >>= 1) s += __shfl_xor(s, off);
      if (lane == 0) scal[d] = s;
    }
  }
}

__global__ void k_ucombine(const float* __restrict__ up, float* __restrict__ u2){
  int i = blockIdx.x * 256 + threadIdx.x;   // 0..2047
  int z = i >> 10, h = i & 1023;
  float s = 0.f;
  #pragma unroll
  for (int c = 0; c < 8; ++c) s += up[(z * 8 + c) * 1024 + h];
  u2[i] = s;
}

// hs f32 -> bf16, fp32-exact gates per row
__global__ __launch_bounds__(256) void k_prepass(const float* __restrict__ hs,
    const float* __restrict__ u2, const float* __restrict__ scal,
    unsigned short* __restrict__ hsb, float* __restrict__ gq, float* __restrict__ gk){
  const int t = threadIdx.x, wid = t >> 6, lane = t & 63;
  const int row = blockIdx.x * 4 + wid;
  const float* hrow = hs + (size_t)row * H;
  const float* u_q = u2;
  const float* u_k = u2 + 1024;
  unsigned short* orow = hsb + (size_t)row * H;
  float sq = 0.f, sk = 0.f;
  #pragma unroll
  for (int c = 0; c < 4; ++c){
    const int idx = (lane + c * 64) * 4;
    float4 v  = *reinterpret_cast<const float4*>(hrow + idx);
    float4 uq = *reinterpret_cast<const float4*>(u_q + idx);
    float4 uk = *reinterpret_cast<const float4*>(u_k + idx);
    ushort4 o; o.x = f2bf(v.x); o.y = f2bf(v.y); o.z = f2bf(v.z); o.w = f2bf(v.w);
    *reinterpret_cast<ushort4*>(orow + idx) = o;
    sq += v.x*uq.x + v.y*uq.y + v.z*uq.z + v.w*uq.w;
    sk += v.x*uk.x + v.y*uk.y + v.z*uk.z + v.w*uk.w;
  }
  #pragma unroll
  for (int off = 32; off > 0; off >>= 1){
    sq += __shfl_xor(sq, off);
    sk += __shfl_xor(sk, off);
  }
  if (lane == 0){
    const int b = row >> 11;
    gq[row] = 1.f / (1.f + __expf(-(sq + scal[0] + scal[2 + b])));
    gk[row] = 1.f / (1.f + __expf(-(sk + scal[1] + scal[10 + b])));
  }
}

// ---------------- 128x128 GEMM (bt form), m97 single-buffer structure ----------------
// 256 threads, 2x2 waves, 64x64 per wave; LDS 32KB tiles + epilogue scratch (40KB total)
// -> 3-4 blocks/CU co-residency (m103: 912 TF ref-checked at this structure).
// MODE 0: merged QKV (N=3072): col-group 0/1 -> gated bf16 (qhat/khat); 2 -> V transposed
// MODE 3: scores*scale -> f32 d_out + fused exp -> bf16 probs + rowsum atomics
// MODE 5: PV normalized by rowsum -> f32 out

#define VM0() do { asm volatile("s_waitcnt vmcnt(0)" ::: "memory"); } while(0)
#define BAR() do { asm volatile("" ::: "memory"); __builtin_amdgcn_s_barrier(); asm volatile("" ::: "memory"); } while(0)

template<int MODE>
__global__ __launch_bounds__(256, 3)
void k_gemm(const unsigned short* __restrict__ A, const unsigned short* __restrict__ B,
            int K, int ldA, int ldB, long long Abatch, long long Bbatch,
            const float* __restrict__ gq, const float* __restrict__ gk,
            const float* __restrict__ bq, const float* __restrict__ bk, const float* __restrict__ bv,
            const float* __restrict__ cq, const float* __restrict__ ck,
            unsigned short* __restrict__ oq, unsigned short* __restrict__ ok, unsigned short* __restrict__ ov,
            float* __restrict__ outf, long long outBatch, float scale, float* __restrict__ rsum)
{
  __shared__ __align__(16) short lds[20480];   // 40 KB: As[8192] + Bs[8192] + epilogue scratch
  short* As = lds;
  short* Bs = lds + 8192;

  const int t = threadIdx.x;
  const int wid = t >> 6, lane = t & 63;
  const int wr = wid >> 1, wc = wid & 1;       // 2x2 wave grid, 64x64 per wave
  const int bz = blockIdx.z;
  const unsigned short* Ab = A + (size_t)bz * (size_t)Abatch;
  const unsigned short* Bb = B + (size_t)bz * (size_t)Bbatch;
  const int row0 = blockIdx.x * 128;
  const int col0 = blockIdx.y * 128;

  // staging: 4 issues per operand per wave; issue i handles chunks c=(wid*4+i)*64+lane
  // chunk c -> tile row r=c>>3, k-slot sl=c&7; source k-chunk = sl ^ (r&7) (involution swizzle)
  const unsigned short* srcA[4];
  const unsigned short* srcB[4];
  #pragma unroll
  for (int i = 0; i < 4; ++i){
    const int c = (wid*4 + i)*64 + lane;
    const int r = c >> 3, sl = c & 7;
    const int kcg = sl ^ (r & 7);
    srcA[i] = Ab + (size_t)(row0 + r) * (size_t)ldA + kcg*8;
    srcB[i] = Bb + (size_t)(col0 + r) * (size_t)ldB + kcg*8;
  }

  f32x4 acc[4][4] = {};
  short8 af[4], bf[4];

  const int nkt = K >> 6;
  for (int kt = 0; kt < nkt; ++kt){
    const int k0 = kt << 6;
    #pragma unroll
    for (int i = 0; i < 4; ++i){
      __builtin_amdgcn_global_load_lds(
        (const __attribute__((address_space(1))) void*)(srcA[i] + k0),
        (__attribute__((address_space(3))) void*)((char*)As + (wid*4 + i)*1024), 16, 0, 0);
      __builtin_amdgcn_global_load_lds(
        (const __attribute__((address_space(1))) void*)(srcB[i] + k0),
        (__attribute__((address_space(3))) void*)((char*)Bs + (wid*4 + i)*1024), 16, 0, 0);
    }
    VM0(); BAR();
    #pragma unroll
    for (int kk = 0; kk < 2; ++kk){
      #pragma unroll
      for (int m = 0; m < 4; ++m){
        const int ar = wr*64 + m*16 + (lane & 15);
        const int ssl = (kk*4 + (lane >> 4)) ^ (ar & 7);
        af[m] = *reinterpret_cast<const short8*>(&As[ar*64 + ssl*8]);
      }
      #pragma unroll
      for (int n = 0; n < 4; ++n){
        const int br = wc*64 + n*16 + (lane & 15);
        const int ssl = (kk*4 + (lane >> 4)) ^ (br & 7);
        bf[n] = *reinterpret_cast<const short8*>(&Bs[br*64 + ssl*8]);
      }
      __builtin_amdgcn_s_setprio(1);
      #pragma unroll
      for (int m = 0; m < 4; ++m)
        #pragma unroll
        for (int n = 0; n < 4; ++n)
          acc[m][n] = __builtin_amdgcn_mfma_f32_16x16x32_bf16(af[m], bf[n], acc[m][n], 0, 0, 0);
      __builtin_amdgcn_s_setprio(0);
    }
    BAR();
  }

  // ---- epilogues ---- (C/D layout m89: col=lane&15, row=(lane>>4)*4+reg)
  if constexpr (MODE == 0){
    const int which = col0 >> 10;        // 0=Q 1=K 2=V
    const int lcol  = col0 & 1023;
    if (which < 2){
      const float* gate = which ? gk : gq;
      const float* bias = which ? bk : bq;
      const float* ctxv = which ? ck : cq;
      unsigned short* outb = which ? ok : oq;
      unsigned short* tp = (unsigned short*)lds;          // [128][136] = 34816 B
      float* gl = (float*)((char*)lds + 34816);           // gate rows [128]
      float* bl = gl + 128;                                // bias cols [128]
      float* cl = bl + 128;                                // ctx  cols [128]
      const int b = row0 >> 11;
      __syncthreads();
      if (t < 128){
        gl[t] = gate[row0 + t];
        bl[t] = bias[lcol + t];
        cl[t] = ctxv[b * H + lcol + t];
      }
      __syncthreads();
      #pragma unroll
      for (int m = 0; m < 4; ++m)
        #pragma unroll
        for (int r = 0; r < 4; ++r){
          const int lr = wr*64 + m*16 + (lane >> 4)*4 + r;
          const float g = gl[lr];
          #pragma unroll
          for (int n = 0; n < 4; ++n){
            const int lc = wc*64 + n*16 + (lane & 15);
            const float q = acc[m][n][r] + bl[lc];
            tp[lr*136 + lc] = f2bf((1.f - g) * q + g * cl[lc]);
          }
        }
      __syncthreads();
      const int rr = t & 127;
      const int cc = (t >> 7) * 64;
      const unsigned short* srcp = tp + rr*136 + cc;
      unsigned short* dst = outb + (size_t)(row0 + rr) * H + lcol + cc;
      #pragma unroll
      for (int i = 0; i < 64; i += 8)
        *reinterpret_cast<ushort8*>(dst + i) = *reinterpret_cast<const ushort8*>(srcp + i);
    } else {
      // V transposed store: tp[h][s], then 128B-contiguous stores along s
      unsigned short* tp = (unsigned short*)lds;   // [128 h][136 s]
      const int bb = row0 >> 11;
      const int s0 = row0 & (S - 1);
      __syncthreads();
      #pragma unroll
      for (int m = 0; m < 4; ++m)
        #pragma unroll
        for (int r = 0; r < 4; ++r){
          const int lr = wr*64 + m*16 + (lane >> 4)*4 + r;      // s local
          #pragma unroll
          for (int n = 0; n < 4; ++n){
            const int lc = wc*64 + n*16 + (lane & 15);          // h local
            tp[lc*136 + lr] = f2bf(acc[m][n][r] + bv[lcol + lc]);
          }
        }
      __syncthreads();
      const int hh = t & 127;
      const int sc = (t >> 7) * 64;
      const unsigned short* srcp = tp + hh*136 + sc;
      unsigned short* vout = ov + (size_t)bb * H * S + (size_t)(lcol + hh) * S + (size_t)(s0 + sc);
      #pragma unroll
      for (int i = 0; i < 64; i += 8)
        *reinterpret_cast<ushort8*>(vout + i) = *reinterpret_cast<const ushort8*>(srcp + i);
    }
  } else if constexpr (MODE == 3){
    // scores f32 -> outf; pe = exp(min(val,80)) bf16 -> oq; per-row sums -> rsum
    float* rowacc = (float*)lds;   // 128 floats
    __syncthreads();
    if (t < 128) rowacc[t] = 0.f;
    __syncthreads();
    #pragma unroll
    for (int m = 0; m < 4; ++m)
      #pragma unroll
      for (int r = 0; r < 4; ++r){
        const int lr = wr*64 + m*16 + (lane >> 4)*4 + r;
        const int grow = row0 + lr;
        float psum = 0.f;
        #pragma unroll
        for (int n = 0; n < 4; ++n){
          const int gcol = col0 + wc*64 + n*16 + (lane & 15);
          const float val = acc[m][n][r] * scale;
          outf[(size_t)bz * (size_t)outBatch + (size_t)grow * S + gcol] = val;
          const float pe = __expf(fminf(val, 80.f));     // clamp: no overflow possible
          const unsigned short pb = f2bf(pe);
          oq[(size_t)bz * (size_t)outBatch + (size_t)grow * S + gcol] = pb;
          psum += bf2f(pb);                               // sum the ROUNDED values
        }
        #pragma unroll
        for (int off = 1; off < 16; off <<= 1) psum += __shfl_xor(psum, off);
        if ((lane & 15) == 0) atomicAdd(&rowacc[lr], psum);
      }
    __syncthreads();
    if (t < 128) atomicAdd(&rsum[bz * S + row0 + t], rowacc[t]);
  } else {
    // MODE 5: PV normalized by rowsum
    float* rs = (float*)lds;
    __syncthreads();
    if (t < 128) rs[t] = 1.f / fmaxf(rsum[bz * S + row0 + t], 1e-35f);
    __syncthreads();
    #pragma unroll
    for (int m = 0; m < 4; ++m)
      #pragma unroll
      for (int r = 0; r < 4; ++r){
        const int lr = wr*64 + m*16 + (lane >> 4)*4 + r;
        const float inv = rs[lr];
        #pragma unroll
        for (int n = 0; n < 4; ++n){
          const int gcol = col0 + wc*64 + n*16 + (lane & 15);
          outf[(size_t)bz * (size_t)outBatch + (size_t)(row0 + lr) * H + gcol] = acc[m][n][r] * inv;
        }
      }
  }
}

// ---------------- launch ----------------
extern "C" void kernel_launch(void* const* d_in, const int* in_sizes, int n_in,
                              void* d_out, int out_size, void* d_ws, size_t ws_size,
                              hipStream_t stream) {
  const float* hs  = (const float*)d_in[0];
  const float* ctx = (const float*)d_in[1];
  const float* Wq  = (const float*)d_in[2];
  const float* bq  = (const float*)d_in[3];
  const float* Wk  = (const float*)d_in[4];
  const float* bk  = (const float*)d_in[5];
  const float* Wv  = (const float*)d_in[6];
  const float* bv  = (const float*)d_in[7];
  const float* Wcq = (const float*)d_in[8];
  const float* Wck = (const float*)d_in[9];
  const float* gqh = (const float*)d_in[10];
  const float* gkh = (const float*)d_in[11];
  const float* gqc = (const float*)d_in[12];
  const float* gkc = (const float*)d_in[13];

  char* ws = (char*)d_ws;    // ~768 MB available
  // probs is [NB,S,S] bf16 = 67,108,864 B — keep full-size slot (R11 lesson).
  unsigned short* hsb   = (unsigned short*)(ws);                   // 33.5 MB
  unsigned short* qhat  = (unsigned short*)(ws + 33554432);        // 33.5 MB
  unsigned short* khat  = (unsigned short*)(ws + 67108864);        // 33.5 MB
  unsigned short* vt    = (unsigned short*)(ws + 100663296);       // 33.5 MB
  unsigned short* probs = (unsigned short*)(ws + 134217728);       // 67.1 MB  [NB,S,S]
  unsigned short* wqb   = (unsigned short*)(ws + 201326592);       // 2 MB (wqb|wkb|wvb contiguous)
  unsigned short* wkb   = (unsigned short*)(ws + 203423744);       // 2 MB
  unsigned short* wvb   = (unsigned short*)(ws + 205520896);       // 2 MB
  float* up    = (float*)(ws + 207618048);                         // 64 KB
  float* u2    = (float*)(ws + 207683584);                         // 8 KB
  float* ctxq  = (float*)(ws + 207691776);                         // 32 KB
  float* ctxk  = (float*)(ws + 207724544);                         // 32 KB
  float* gq    = (float*)(ws + 207757312);                         // 64 KB
  float* gk    = (float*)(ws + 207822848);                         // 64 KB
  float* scal  = (float*)(ws + 207888384);                         // 256 B
  float* rsum  = (float*)(ws + 207888640);                         // 64 KB (per-row exp sums)

  float* out_attn   = (float*)d_out;                        // [NB,S,H]
  float* out_scores = out_attn + (size_t)MROWS * H;         // [NB,S,S]

  // zero rowsum accumulators (64 KB)
  hipMemsetAsync(rsum, 0, MROWS * sizeof(float), stream);

  // merged prep (1 dispatch) + combine (1)
  k_prep<<<3649, 256, 0, stream>>>(Wq, Wk, Wv, Wcq, Wck, ctx, gqh, gkh, bq, bk, gqc, gkc,
      wqb, wkb, wvb, up, ctxq, ctxk, scal);
  k_ucombine<<<8, 256, 0, stream>>>(up, u2);
  k_prepass<<<MROWS / 4, 256, 0, stream>>>(hs, u2, scal, hsb, gq, gk);

  // merged QKV projections (M=16384, N=3072, K=1024), 128^2 tiles — 3072 blocks
  k_gemm<0><<<dim3(128, 24, 1), 256, 0, stream>>>(hsb, wqb, 1024, 1024, 1024, 0, 0,
      gq, gk, bq, bk, bv, ctxq, ctxk, qhat, khat, vt, nullptr, 0, 1.f, nullptr);

  // scores + fused exp/probs/rowsum (per batch M=N=2048, K=1024) — 2048 blocks
  k_gemm<3><<<dim3(16, 16, 8), 256, 0, stream>>>(qhat, khat, 1024, 1024, 1024,
      (long long)S * H, (long long)S * H,
      nullptr, nullptr, nullptr, nullptr, nullptr, nullptr, nullptr,
      probs, nullptr, nullptr, out_scores, (long long)S * S, 0.03125f, rsum);

  // output = (probs @ V) / rowsum (per batch M=2048, N=1024, K=2048) — 1024 blocks
  k_gemm<5><<<dim3(16, 8, 8), 256, 0, stream>>>(probs, vt, 2048, 2048, 2048,
      (long long)S * S, (long long)H * S,
      nullptr, nullptr, nullptr, nullptr, nullptr, nullptr, nullptr,
      nullptr, nullptr, nullptr, out_attn, (long long)S * H, 1.f, rsum);
}

// Round 14
// 322.599 us; speedup vs baseline: 1.0657x; 1.0657x over previous
//
#include <hip/hip_runtime.h>
#include <cstdint>
#include <cstddef>

#define H 1024
#define NB 8
#define S 2048
#define MROWS (NB*S)

using short8  = __attribute__((ext_vector_type(8))) short;
using ushort8 = __attribute__((ext_vector_type(8))) unsigned short;
using f32x4   = __attribute__((ext_vector_type(4))) float;

__device__ __forceinline__ unsigned short f2bf(float f){
  union { float f; unsigned int u; } c; c.f = f;
  unsigned int u = c.u;
  return (unsigned short)((u + 0x7fffu + ((u >> 16) & 1u)) >> 16);
}
__device__ __forceinline__ float bf2f(unsigned short b){
  union { unsigned int u; float f; } c; c.u = ((unsigned int)b) << 16;
  return c.f;
}

// ---------------- merged prep kernel ----------------
__global__ __launch_bounds__(256) void k_prep(
    const float* __restrict__ Wq, const float* __restrict__ Wk, const float* __restrict__ Wv,
    const float* __restrict__ Wcq, const float* __restrict__ Wck, const float* __restrict__ ctx,
    const float* __restrict__ gqh, const float* __restrict__ gkh,
    const float* __restrict__ bq, const float* __restrict__ bk,
    const float* __restrict__ gqc, const float* __restrict__ gkc,
    unsigned short* __restrict__ wqb, unsigned short* __restrict__ wkb, unsigned short* __restrict__ wvb,
    float* __restrict__ up, float* __restrict__ ctxq, float* __restrict__ ctxk,
    float* __restrict__ scal)
{
  __shared__ float cs[NB * H];
  const int bid = blockIdx.x;
  const int t = threadIdx.x;
  if (bid < 3072){
    const int y = bid >> 10;
    const int x = bid & 1023;
    const float* src = y == 0 ? Wq : (y == 1 ? Wk : Wv);
    unsigned short* dst = y == 0 ? wqb : (y == 1 ? wkb : wvb);
    const int i = (x * 256 + t) * 4;
    float4 v = *reinterpret_cast<const float4*>(src + i);
    ushort4 o; o.x = f2bf(v.x); o.y = f2bf(v.y); o.z = f2bf(v.z); o.w = f2bf(v.w);
    *reinterpret_cast<ushort4*>(dst + i) = o;
  } else if (bid < 3136){
    const int sub = bid - 3072;
    const int z = sub >> 5;
    const int y = (sub >> 2) & 7;
    const int x = sub & 3;
    const float* W = z ? Wk : Wq;
    const float* g = z ? gkh : gqh;
    const int in = x * 256 + t;
    const int o0 = y * 128;
    float s = 0.f;
    for (int o = 0; o < 128; ++o) s = fmaf(W[(size_t)(o0 + o) * H + in], g[o0 + o], s);
    up[(z * 8 + y) * 1024 + in] = s;
  } else if (bid < 3648){
    const int sub = bid - 3136;
    const int y = sub >> 8;
    const int x = sub & 255;
    const float* W = y ? Wck : Wcq;
    float* out = y ? ctxk : ctxq;
    for (int i = t; i < NB * H; i += 256) cs[i] = ctx[i];
    __syncthreads();
    const int wid = t >> 6, lane = t & 63;
    const int row = x * 4 + wid;
    float a[NB];
    #pragma unroll
    for (int b = 0; b < NB; ++b) a[b] = 0.f;
    for (int i0 = 0; i0 < H; i0 += 64){
      const float w = W[(size_t)row * H + i0 + lane];
      #pragma unroll
      for (int b = 0; b < NB; ++b) a[b] = fmaf(w, cs[b * H + i0 + lane], a[b]);
    }
    #pragma unroll
    for (int b = 0; b < NB; ++b){
      float v = a[b];
      #pragma unroll
      for (int off = 32; off > 0; off >>= 1) v += __shfl_xor(v, off);
      if (lane == 0) out[b * H + row] = v;
    }
  } else {
    const int wid = t >> 6, lane = t & 63;
    for (int d = wid; d < 18; d += 4){
      const float *pa, *pb;
      if (d == 0){ pa = bq; pb = gqh; }
      else if (d == 1){ pa = bk; pb = gkh; }
      else if (d < 10){ pa = ctx + (d - 2) * H; pb = gqc; }
      else { pa = ctx + (d - 10) * H; pb = gkc; }
      float s = 0.f;
      for (int i = lane; i < H; i += 64) s = fmaf(pa[i], pb[i], s);
      #pragma unroll
      for (int off = 32; off > 0; off >>= 1) s += __shfl_xor(s, off);
      if (lane == 0) scal[d] = s;
    }
  }
}

__global__ void k_ucombine(const float* __restrict__ up, float* __restrict__ u2){
  int i = blockIdx.x * 256 + threadIdx.x;
  int z = i >> 10, h = i & 1023;
  float s = 0.f;
  #pragma unroll
  for (int c = 0; c < 8; ++c) s += up[(z * 8 + c) * 1024 + h];
  u2[i] = s;
}

__global__ __launch_bounds__(256) void k_prepass(const float* __restrict__ hs,
    const float* __restrict__ u2, const float* __restrict__ scal,
    unsigned short* __restrict__ hsb, float* __restrict__ gq, float* __restrict__ gk){
  const int t = threadIdx.x, wid = t >> 6, lane = t & 63;
  const int row = blockIdx.x * 4 + wid;
  const float* hrow = hs + (size_t)row * H;
  const float* u_q = u2;
  const float* u_k = u2 + 1024;
  unsigned short* orow = hsb + (size_t)row * H;
  float sq = 0.f, sk = 0.f;
  #pragma unroll
  for (int c = 0; c < 4; ++c){
    const int idx = (lane + c * 64) * 4;
    float4 v  = *reinterpret_cast<const float4*>(hrow + idx);
    float4 uq = *reinterpret_cast<const float4*>(u_q + idx);
    float4 uk = *reinterpret_cast<const float4*>(u_k + idx);
    ushort4 o; o.x = f2bf(v.x); o.y = f2bf(v.y); o.z = f2bf(v.z); o.w = f2bf(v.w);
    *reinterpret_cast<ushort4*>(orow + idx) = o;
    sq += v.x*uq.x + v.y*uq.y + v.z*uq.z + v.w*uq.w;
    sk += v.x*uk.x + v.y*uk.y + v.z*uk.z + v.w*uk.w;
  }
  #pragma unroll
  for (int off = 32; off > 0; off >>= 1){
    sq += __shfl_xor(sq, off);
    sk += __shfl_xor(sk, off);
  }
  if (lane == 0){
    const int b = row >> 11;
    gq[row] = 1.f / (1.f + __expf(-(sq + scal[0] + scal[2 + b])));
    gk[row] = 1.f / (1.f + __expf(-(sk + scal[1] + scal[10 + b])));
  }
}

#define VM4() do { asm volatile("s_waitcnt vmcnt(4)" ::: "memory"); } while(0)
#define VM0() do { asm volatile("s_waitcnt vmcnt(0)" ::: "memory"); } while(0)
#define BAR() do { asm volatile("" ::: "memory"); __builtin_amdgcn_s_barrier(); asm volatile("" ::: "memory"); } while(0)

// ---------------- 128x128 GEMM (m97 structure) — QKV only (fetch-light, compute-bound) ----------------
__global__ __launch_bounds__(256, 3)
void k_gemm128(const unsigned short* __restrict__ A, const unsigned short* __restrict__ B,
            int K, int ldA, int ldB,
            const float* __restrict__ gq, const float* __restrict__ gk,
            const float* __restrict__ bq, const float* __restrict__ bk, const float* __restrict__ bv,
            const float* __restrict__ cq, const float* __restrict__ ck,
            unsigned short* __restrict__ oq, unsigned short* __restrict__ ok, unsigned short* __restrict__ ov)
{
  __shared__ __align__(16) short lds[20480];   // 40 KB
  short* As = lds;
  short* Bs = lds + 8192;

  const int t = threadIdx.x;
  const int wid = t >> 6, lane = t & 63;
  const int wr = wid >> 1, wc = wid & 1;
  const int row0 = blockIdx.x * 128;
  const int col0 = blockIdx.y * 128;

  const unsigned short* srcA[4];
  const unsigned short* srcB[4];
  #pragma unroll
  for (int i = 0; i < 4; ++i){
    const int c = (wid*4 + i)*64 + lane;
    const int r = c >> 3, sl = c & 7;
    const int kcg = sl ^ (r & 7);
    srcA[i] = A + (size_t)(row0 + r) * (size_t)ldA + kcg*8;
    srcB[i] = B + (size_t)(col0 + r) * (size_t)ldB + kcg*8;
  }

  f32x4 acc[4][4] = {};
  short8 af[4], bf[4];

  const int nkt = K >> 6;
  for (int kt = 0; kt < nkt; ++kt){
    const int k0 = kt << 6;
    #pragma unroll
    for (int i = 0; i < 4; ++i){
      __builtin_amdgcn_global_load_lds(
        (const __attribute__((address_space(1))) void*)(srcA[i] + k0),
        (__attribute__((address_space(3))) void*)((char*)As + (wid*4 + i)*1024), 16, 0, 0);
      __builtin_amdgcn_global_load_lds(
        (const __attribute__((address_space(1))) void*)(srcB[i] + k0),
        (__attribute__((address_space(3))) void*)((char*)Bs + (wid*4 + i)*1024), 16, 0, 0);
    }
    VM0(); BAR();
    #pragma unroll
    for (int kk = 0; kk < 2; ++kk){
      #pragma unroll
      for (int m = 0; m < 4; ++m){
        const int ar = wr*64 + m*16 + (lane & 15);
        const int ssl = (kk*4 + (lane >> 4)) ^ (ar & 7);
        af[m] = *reinterpret_cast<const short8*>(&As[ar*64 + ssl*8]);
      }
      #pragma unroll
      for (int n = 0; n < 4; ++n){
        const int br = wc*64 + n*16 + (lane & 15);
        const int ssl = (kk*4 + (lane >> 4)) ^ (br & 7);
        bf[n] = *reinterpret_cast<const short8*>(&Bs[br*64 + ssl*8]);
      }
      __builtin_amdgcn_s_setprio(1);
      #pragma unroll
      for (int m = 0; m < 4; ++m)
        #pragma unroll
        for (int n = 0; n < 4; ++n)
          acc[m][n] = __builtin_amdgcn_mfma_f32_16x16x32_bf16(af[m], bf[n], acc[m][n], 0, 0, 0);
      __builtin_amdgcn_s_setprio(0);
    }
    BAR();
  }

  // epilogue (C/D layout m89)
  const int which = col0 >> 10;        // 0=Q 1=K 2=V
  const int lcol  = col0 & 1023;
  if (which < 2){
    const float* gate = which ? gk : gq;
    const float* bias = which ? bk : bq;
    const float* ctxv = which ? ck : cq;
    unsigned short* outb = which ? ok : oq;
    unsigned short* tp = (unsigned short*)lds;          // [128][136]
    float* gl = (float*)((char*)lds + 34816);
    float* bl = gl + 128;
    float* cl = bl + 128;
    const int b = row0 >> 11;
    __syncthreads();
    if (t < 128){
      gl[t] = gate[row0 + t];
      bl[t] = bias[lcol + t];
      cl[t] = ctxv[b * H + lcol + t];
    }
    __syncthreads();
    #pragma unroll
    for (int m = 0; m < 4; ++m)
      #pragma unroll
      for (int r = 0; r < 4; ++r){
        const int lr = wr*64 + m*16 + (lane >> 4)*4 + r;
        const float g = gl[lr];
        #pragma unroll
        for (int n = 0; n < 4; ++n){
          const int lc = wc*64 + n*16 + (lane & 15);
          const float q = acc[m][n][r] + bl[lc];
          tp[lr*136 + lc] = f2bf((1.f - g) * q + g * cl[lc]);
        }
      }
    __syncthreads();
    const int rr = t & 127;
    const int cc = (t >> 7) * 64;
    const unsigned short* srcp = tp + rr*136 + cc;
    unsigned short* dst = outb + (size_t)(row0 + rr) * H + lcol + cc;
    #pragma unroll
    for (int i = 0; i < 64; i += 8)
      *reinterpret_cast<ushort8*>(dst + i) = *reinterpret_cast<const ushort8*>(srcp + i);
  } else {
    unsigned short* tp = (unsigned short*)lds;   // [128 h][136 s]
    const int bb = row0 >> 11;
    const int s0 = row0 & (S - 1);
    __syncthreads();
    #pragma unroll
    for (int m = 0; m < 4; ++m)
      #pragma unroll
      for (int r = 0; r < 4; ++r){
        const int lr = wr*64 + m*16 + (lane >> 4)*4 + r;      // s local
        #pragma unroll
        for (int n = 0; n < 4; ++n){
          const int lc = wc*64 + n*16 + (lane & 15);          // h local
          tp[lc*136 + lr] = f2bf(acc[m][n][r] + bv[lcol + lc]);
        }
      }
    __syncthreads();
    const int hh = t & 127;
    const int sc = (t >> 7) * 64;
    const unsigned short* srcp = tp + hh*136 + sc;
    unsigned short* vout = ov + (size_t)bb * H * S + (size_t)(lcol + hh) * S + (size_t)(s0 + sc);
    #pragma unroll
    for (int i = 0; i < 64; i += 8)
      *reinterpret_cast<ushort8*>(vout + i) = *reinterpret_cast<const ushort8*>(srcp + i);
  }
}

// ---------------- 256x256 GEMM (R2 single-barrier schedule) — scores & PV (fetch-heavy) ----------------
// MODE 3: scores*scale -> f32 d_out + fused exp -> bf16 probs + rowsum atomics
// MODE 5: PV normalized by rowsum -> f32 out

#define STG(bufi, opi, halfi, koff, P0, P1) \
  do { __builtin_amdgcn_global_load_lds((const __attribute__((address_space(1))) void*)(P0 + (koff)), \
      (__attribute__((address_space(3))) void*)((char*)(&lds[bufi][opi][halfi][0]) + (wid*2+0)*1024), 16, 0, 0); \
    __builtin_amdgcn_global_load_lds((const __attribute__((address_space(1))) void*)(P1 + (koff)), \
      (__attribute__((address_space(3))) void*)((char*)(&lds[bufi][opi][halfi][0]) + (wid*2+1)*1024), 16, 0, 0); } while(0)
#define STG_A(bufi, halfi, koff) STG(bufi, 0, halfi, koff, sA0, sA1)
#define STG_B(bufi, halfi, koff) STG(bufi, 1, halfi, koff, sB0, sB1)

#define DS_A(bufi, ks, mh) \
  do { _Pragma("unroll") for (int m_ = 0; m_ < 4; ++m_){ \
      const int ar_ = wr*128 + ((mh)*4 + m_)*16 + (lane & 15); \
      const int sl_ = (lane >> 4) ^ ((ar_ >> 1) & 3); \
      af[m_] = *reinterpret_cast<const short8*>(&lds[bufi][0][ks][ar_*32 + sl_*8]); } } while(0)
#define DS_B(bufi, ks) \
  do { _Pragma("unroll") for (int n_ = 0; n_ < 4; ++n_){ \
      const int br_ = wc*64 + n_*16 + (lane & 15); \
      const int sl_ = (lane >> 4) ^ ((br_ >> 1) & 3); \
      bf[n_] = *reinterpret_cast<const short8*>(&lds[bufi][1][ks][br_*32 + sl_*8]); } } while(0)
#define MFMA16(mh) \
  do { __builtin_amdgcn_s_setprio(1); \
    _Pragma("unroll") for (int m_ = 0; m_ < 4; ++m_) \
      _Pragma("unroll") for (int n_ = 0; n_ < 4; ++n_) \
        acc[(mh)*4 + m_][n_] = __builtin_amdgcn_mfma_f32_16x16x32_bf16(af[m_], bf[n_], acc[(mh)*4 + m_][n_], 0, 0, 0); \
    __builtin_amdgcn_s_setprio(0); } while(0)

template<int MODE>
__global__ __launch_bounds__(512, 2)
void k_gemm256(const unsigned short* __restrict__ A, const unsigned short* __restrict__ B,
            int K, int ldA, int ldB, long long Abatch, long long Bbatch,
            unsigned short* __restrict__ oq,
            float* __restrict__ outf, long long outBatch, float scale, float* __restrict__ rsum)
{
  __shared__ __align__(16) short lds[2][2][2][8192];

  const int t = threadIdx.x;
  const int wid = t >> 6, lane = t & 63;
  const int wr = wid >> 2, wc = wid & 3;
  const int bz = blockIdx.z;
  const unsigned short* Ab = A + (size_t)bz * (size_t)Abatch;
  const unsigned short* Bb = B + (size_t)bz * (size_t)Bbatch;
  const int row0 = blockIdx.x * 256;
  const int col0 = blockIdx.y * 256;

  const int c0 = (wid*2 + 0)*64 + lane;
  const int c1 = (wid*2 + 1)*64 + lane;
  const int r0s = c0 >> 2, r1s = c1 >> 2;
  const int kc0 = (c0 & 3) ^ ((r0s >> 1) & 3);
  const int kc1 = (c1 & 3) ^ ((r1s >> 1) & 3);
  const unsigned short* sA0 = Ab + (size_t)(row0 + r0s) * (size_t)ldA + kc0*8;
  const unsigned short* sA1 = Ab + (size_t)(row0 + r1s) * (size_t)ldA + kc1*8;
  const unsigned short* sB0 = Bb + (size_t)(col0 + r0s) * (size_t)ldB + kc0*8;
  const unsigned short* sB1 = Bb + (size_t)(col0 + r1s) * (size_t)ldB + kc1*8;

  f32x4 acc[8][4] = {};
  short8 af[4], bf[4];

  STG_A(0, 0, 0); STG_B(0, 0, 0); STG_A(0, 1, 32); STG_B(0, 1, 32);
  VM0(); BAR();

  const int niter = K >> 7;
  for (int it = 0; it < niter; ++it){
    const int t1k = (it*2 + 1) << 6;
    const int t2k = (it*2 + 2) << 6;
    const bool more = (it + 1 < niter);
    DS_A(0, 0, 0); DS_B(0, 0); STG_A(1, 0, t1k);      MFMA16(0);                              BAR();
    DS_A(0, 0, 1);             STG_B(1, 0, t1k);      MFMA16(1); VM4();                       BAR();
    DS_A(0, 1, 0); DS_B(0, 1); STG_A(1, 1, t1k + 32); MFMA16(0);                              BAR();
    DS_A(0, 1, 1);             STG_B(1, 1, t1k + 32); MFMA16(1); if (more) { VM4(); } else { VM0(); } BAR();
    DS_A(1, 0, 0); DS_B(1, 0); if (more) { STG_A(0, 0, t2k); }      MFMA16(0);                BAR();
    DS_A(1, 0, 1);             if (more) { STG_B(0, 0, t2k); }      MFMA16(1); if (more) { VM4(); } BAR();
    DS_A(1, 1, 0); DS_B(1, 1); if (more) { STG_A(0, 1, t2k + 32); } MFMA16(0);                BAR();
    DS_A(1, 1, 1);             if (more) { STG_B(0, 1, t2k + 32); } MFMA16(1); if (more) { VM4(); } BAR();
  }

  if constexpr (MODE == 3){
    float* rowacc = (float*)lds;
    __syncthreads();
    if (t < 256) rowacc[t] = 0.f;
    __syncthreads();
    #pragma unroll
    for (int mi = 0; mi < 8; ++mi)
      #pragma unroll
      for (int r = 0; r < 4; ++r){
        const int lr = wr*128 + mi*16 + (lane >> 4)*4 + r;
        const int grow = row0 + lr;
        float psum = 0.f;
        #pragma unroll
        for (int n = 0; n < 4; ++n){
          const int gcol = col0 + wc*64 + n*16 + (lane & 15);
          const float val = acc[mi][n][r] * scale;
          outf[(size_t)bz * (size_t)outBatch + (size_t)grow * S + gcol] = val;
          const float pe = __expf(fminf(val, 80.f));
          const unsigned short pb = f2bf(pe);
          oq[(size_t)bz * (size_t)outBatch + (size_t)grow * S + gcol] = pb;
          psum += bf2f(pb);
        }
        #pragma unroll
        for (int off = 1; off < 16; off <<= 1) psum += __shfl_xor(psum, off);
        if ((lane & 15) == 0) atomicAdd(&rowacc[lr], psum);
      }
    __syncthreads();
    if (t < 256) atomicAdd(&rsum[bz * S + row0 + t], rowacc[t]);
  } else {
    float* rs = (float*)lds;
    __syncthreads();
    if (t < 256) rs[t] = 1.f / fmaxf(rsum[bz * S + row0 + t], 1e-35f);
    __syncthreads();
    #pragma unroll
    for (int mi = 0; mi < 8; ++mi)
      #pragma unroll
      for (int r = 0; r < 4; ++r){
        const int lr = wr*128 + mi*16 + (lane >> 4)*4 + r;
        const float inv = rs[lr];
        #pragma unroll
        for (int n = 0; n < 4; ++n){
          const int gcol = col0 + wc*64 + n*16 + (lane & 15);
          outf[(size_t)bz * (size_t)outBatch + (size_t)(row0 + lr) * H + gcol] = acc[mi][n][r] * inv;
        }
      }
  }
}

// ---------------- launch ----------------
extern "C" void kernel_launch(void* const* d_in, const int* in_sizes, int n_in,
                              void* d_out, int out_size, void* d_ws, size_t ws_size,
                              hipStream_t stream) {
  const float* hs  = (const float*)d_in[0];
  const float* ctx = (const float*)d_in[1];
  const float* Wq  = (const float*)d_in[2];
  const float* bq  = (const float*)d_in[3];
  const float* Wk  = (const float*)d_in[4];
  const float* bk  = (const float*)d_in[5];
  const float* Wv  = (const float*)d_in[6];
  const float* bv  = (const float*)d_in[7];
  const float* Wcq = (const float*)d_in[8];
  const float* Wck = (const float*)d_in[9];
  const float* gqh = (const float*)d_in[10];
  const float* gkh = (const float*)d_in[11];
  const float* gqc = (const float*)d_in[12];
  const float* gkc = (const float*)d_in[13];

  char* ws = (char*)d_ws;    // ~768 MB available
  // probs is [NB,S,S] bf16 = 67,108,864 B — full-size slot (R11 lesson).
  unsigned short* hsb   = (unsigned short*)(ws);                   // 33.5 MB
  unsigned short* qhat  = (unsigned short*)(ws + 33554432);        // 33.5 MB
  unsigned short* khat  = (unsigned short*)(ws + 67108864);        // 33.5 MB
  unsigned short* vt    = (unsigned short*)(ws + 100663296);       // 33.5 MB
  unsigned short* probs = (unsigned short*)(ws + 134217728);       // 67.1 MB  [NB,S,S]
  unsigned short* wqb   = (unsigned short*)(ws + 201326592);       // 2 MB (wqb|wkb|wvb contiguous)
  unsigned short* wkb   = (unsigned short*)(ws + 203423744);       // 2 MB
  unsigned short* wvb   = (unsigned short*)(ws + 205520896);       // 2 MB
  float* up    = (float*)(ws + 207618048);                         // 64 KB
  float* u2    = (float*)(ws + 207683584);                         // 8 KB
  float* ctxq  = (float*)(ws + 207691776);                         // 32 KB
  float* ctxk  = (float*)(ws + 207724544);                         // 32 KB
  float* gq    = (float*)(ws + 207757312);                         // 64 KB
  float* gk    = (float*)(ws + 207822848);                         // 64 KB
  float* scal  = (float*)(ws + 207888384);                         // 256 B
  float* rsum  = (float*)(ws + 207888640);                         // 64 KB

  float* out_attn   = (float*)d_out;                        // [NB,S,H]
  float* out_scores = out_attn + (size_t)MROWS * H;         // [NB,S,S]

  hipMemsetAsync(rsum, 0, MROWS * sizeof(float), stream);

  k_prep<<<3649, 256, 0, stream>>>(Wq, Wk, Wv, Wcq, Wck, ctx, gqh, gkh, bq, bk, gqc, gkc,
      wqb, wkb, wvb, up, ctxq, ctxk, scal);
  k_ucombine<<<8, 256, 0, stream>>>(up, u2);
  k_prepass<<<MROWS / 4, 256, 0, stream>>>(hs, u2, scal, hsb, gq, gk);

  // merged QKV (M=16384, N=3072, K=1024), 128^2 tiles (compute-bound: R13 124us)
  k_gemm128<<<dim3(128, 24, 1), 256, 0, stream>>>(hsb, wqb, 1024, 1024, 1024,
      gq, gk, bq, bk, bv, ctxq, ctxk, qhat, khat, vt);

  // scores + fused exp/probs/rowsum (per batch M=N=2048, K=1024), 256^2 tiles (fetch-heavy)
  k_gemm256<3><<<dim3(8, 8, 8), 512, 0, stream>>>(qhat, khat, 1024, 1024, 1024,
      (long long)S * H, (long long)S * H,
      probs, out_scores, (long long)S * S, 0.03125f, rsum);

  // output = (probs @ V) / rowsum (per batch M=2048, N=1024, K=2048), 256^2 tiles
  k_gemm256<5><<<dim3(8, 4, 8), 512, 0, stream>>>(probs, vt, 2048, 2048, 2048,
      (long long)S * S, (long long)H * S,
      nullptr, out_attn, (long long)S * H, 1.f, rsum);
}

// Round 15
// 322.137 us; speedup vs baseline: 1.0672x; 1.0014x over previous
//
#include <hip/hip_runtime.h>
#include <cstdint>
#include <cstddef>

#define H 1024
#define NB 8
#define S 2048
#define MROWS (NB*S)

using short8  = __attribute__((ext_vector_type(8))) short;
using ushort8 = __attribute__((ext_vector_type(8))) unsigned short;
using f32x4   = __attribute__((ext_vector_type(4))) float;

__device__ __forceinline__ unsigned short f2bf(float f){
  union { float f; unsigned int u; } c; c.f = f;
  unsigned int u = c.u;
  return (unsigned short)((u + 0x7fffu + ((u >> 16) & 1u)) >> 16);
}
__device__ __forceinline__ float bf2f(unsigned short b){
  union { unsigned int u; float f; } c; c.u = ((unsigned int)b) << 16;
  return c.f;
}

// ---------------- merged prep kernel ----------------
__global__ __launch_bounds__(256) void k_prep(
    const float* __restrict__ Wq, const float* __restrict__ Wk, const float* __restrict__ Wv,
    const float* __restrict__ Wcq, const float* __restrict__ Wck, const float* __restrict__ ctx,
    const float* __restrict__ gqh, const float* __restrict__ gkh,
    const float* __restrict__ bq, const float* __restrict__ bk,
    const float* __restrict__ gqc, const float* __restrict__ gkc,
    unsigned short* __restrict__ wqb, unsigned short* __restrict__ wkb, unsigned short* __restrict__ wvb,
    float* __restrict__ up, float* __restrict__ ctxq, float* __restrict__ ctxk,
    float* __restrict__ scal)
{
  __shared__ float cs[NB * H];
  const int bid = blockIdx.x;
  const int t = threadIdx.x;
  if (bid < 3072){
    const int y = bid >> 10;
    const int x = bid & 1023;
    const float* src = y == 0 ? Wq : (y == 1 ? Wk : Wv);
    unsigned short* dst = y == 0 ? wqb : (y == 1 ? wkb : wvb);
    const int i = (x * 256 + t) * 4;
    float4 v = *reinterpret_cast<const float4*>(src + i);
    ushort4 o; o.x = f2bf(v.x); o.y = f2bf(v.y); o.z = f2bf(v.z); o.w = f2bf(v.w);
    *reinterpret_cast<ushort4*>(dst + i) = o;
  } else if (bid < 3136){
    const int sub = bid - 3072;
    const int z = sub >> 5;
    const int y = (sub >> 2) & 7;
    const int x = sub & 3;
    const float* W = z ? Wk : Wq;
    const float* g = z ? gkh : gqh;
    const int in = x * 256 + t;
    const int o0 = y * 128;
    float s = 0.f;
    for (int o = 0; o < 128; ++o) s = fmaf(W[(size_t)(o0 + o) * H + in], g[o0 + o], s);
    up[(z * 8 + y) * 1024 + in] = s;
  } else if (bid < 3648){
    const int sub = bid - 3136;
    const int y = sub >> 8;
    const int x = sub & 255;
    const float* W = y ? Wck : Wcq;
    float* out = y ? ctxk : ctxq;
    for (int i = t; i < NB * H; i += 256) cs[i] = ctx[i];
    __syncthreads();
    const int wid = t >> 6, lane = t & 63;
    const int row = x * 4 + wid;
    float a[NB];
    #pragma unroll
    for (int b = 0; b < NB; ++b) a[b] = 0.f;
    for (int i0 = 0; i0 < H; i0 += 64){
      const float w = W[(size_t)row * H + i0 + lane];
      #pragma unroll
      for (int b = 0; b < NB; ++b) a[b] = fmaf(w, cs[b * H + i0 + lane], a[b]);
    }
    #pragma unroll
    for (int b = 0; b < NB; ++b){
      float v = a[b];
      #pragma unroll
      for (int off = 32; off > 0; off >>= 1) v += __shfl_xor(v, off);
      if (lane == 0) out[b * H + row] = v;
    }
  } else {
    const int wid = t >> 6, lane = t & 63;
    for (int d = wid; d < 18; d += 4){
      const float *pa, *pb;
      if (d == 0){ pa = bq; pb = gqh; }
      else if (d == 1){ pa = bk; pb = gkh; }
      else if (d < 10){ pa = ctx + (d - 2) * H; pb = gqc; }
      else { pa = ctx + (d - 10) * H; pb = gkc; }
      float s = 0.f;
      for (int i = lane; i < H; i += 64) s = fmaf(pa[i], pb[i], s);
      #pragma unroll
      for (int off = 32; off > 0; off >>= 1) s += __shfl_xor(s, off);
      if (lane == 0) scal[d] = s;
    }
  }
}

__global__ void k_ucombine(const float* __restrict__ up, float* __restrict__ u2){
  int i = blockIdx.x * 256 + threadIdx.x;
  int z = i >> 10, h = i & 1023;
  float s = 0.f;
  #pragma unroll
  for (int c = 0; c < 8; ++c) s += up[(z * 8 + c) * 1024 + h];
  u2[i] = s;
}

__global__ __launch_bounds__(256) void k_prepass(const float* __restrict__ hs,
    const float* __restrict__ u2, const float* __restrict__ scal,
    unsigned short* __restrict__ hsb, float* __restrict__ gq, float* __restrict__ gk){
  const int t = threadIdx.x, wid = t >> 6, lane = t & 63;
  const int row = blockIdx.x * 4 + wid;
  const float* hrow = hs + (size_t)row * H;
  const float* u_q = u2;
  const float* u_k = u2 + 1024;
  unsigned short* orow = hsb + (size_t)row * H;
  float sq = 0.f, sk = 0.f;
  #pragma unroll
  for (int c = 0; c < 4; ++c){
    const int idx = (lane + c * 64) * 4;
    float4 v  = *reinterpret_cast<const float4*>(hrow + idx);
    float4 uq = *reinterpret_cast<const float4*>(u_q + idx);
    float4 uk = *reinterpret_cast<const float4*>(u_k + idx);
    ushort4 o; o.x = f2bf(v.x); o.y = f2bf(v.y); o.z = f2bf(v.z); o.w = f2bf(v.w);
    *reinterpret_cast<ushort4*>(orow + idx) = o;
    sq += v.x*uq.x + v.y*uq.y + v.z*uq.z + v.w*uq.w;
    sk += v.x*uk.x + v.y*uk.y + v.z*uk.z + v.w*uk.w;
  }
  #pragma unroll
  for (int off = 32; off > 0; off >>= 1){
    sq += __shfl_xor(sq, off);
    sk += __shfl_xor(sk, off);
  }
  if (lane == 0){
    const int b = row >> 11;
    gq[row] = 1.f / (1.f + __expf(-(sq + scal[0] + scal[2 + b])));
    gk[row] = 1.f / (1.f + __expf(-(sk + scal[1] + scal[10 + b])));
  }
}

#define VM4() do { asm volatile("s_waitcnt vmcnt(4)" ::: "memory"); } while(0)
#define VM0() do { asm volatile("s_waitcnt vmcnt(0)" ::: "memory"); } while(0)
#define BAR() do { asm volatile("" ::: "memory"); __builtin_amdgcn_s_barrier(); asm volatile("" ::: "memory"); } while(0)

// ---------------- 128x128 GEMM (m97 structure) — QKV only ----------------
// Grid: x = col-group (FASTEST, 24), y = row (128) -> consecutive blocks share
// the same 256KB A-panel (L2-resident); 6MB weights stay L3-hot.
__global__ __launch_bounds__(256, 4)
void k_gemm128(const unsigned short* __restrict__ A, const unsigned short* __restrict__ B,
            int K, int ldA, int ldB,
            const float* __restrict__ gq, const float* __restrict__ gk,
            const float* __restrict__ bq, const float* __restrict__ bk, const float* __restrict__ bv,
            const float* __restrict__ cq, const float* __restrict__ ck,
            unsigned short* __restrict__ oq, unsigned short* __restrict__ ok, unsigned short* __restrict__ ov)
{
  __shared__ __align__(16) short lds[20480];   // 40 KB -> 4 blocks/CU
  short* As = lds;
  short* Bs = lds + 8192;

  const int t = threadIdx.x;
  const int wid = t >> 6, lane = t & 63;
  const int wr = wid >> 1, wc = wid & 1;
  const int row0 = blockIdx.y * 128;     // y = row (slow)
  const int col0 = blockIdx.x * 128;     // x = col (fast)

  const unsigned short* srcA[4];
  const unsigned short* srcB[4];
  #pragma unroll
  for (int i = 0; i < 4; ++i){
    const int c = (wid*4 + i)*64 + lane;
    const int r = c >> 3, sl = c & 7;
    const int kcg = sl ^ (r & 7);
    srcA[i] = A + (size_t)(row0 + r) * (size_t)ldA + kcg*8;
    srcB[i] = B + (size_t)(col0 + r) * (size_t)ldB + kcg*8;
  }

  f32x4 acc[4][4] = {};
  short8 af[4], bf[4];

  const int nkt = K >> 6;
  for (int kt = 0; kt < nkt; ++kt){
    const int k0 = kt << 6;
    #pragma unroll
    for (int i = 0; i < 4; ++i){
      __builtin_amdgcn_global_load_lds(
        (const __attribute__((address_space(1))) void*)(srcA[i] + k0),
        (__attribute__((address_space(3))) void*)((char*)As + (wid*4 + i)*1024), 16, 0, 0);
      __builtin_amdgcn_global_load_lds(
        (const __attribute__((address_space(1))) void*)(srcB[i] + k0),
        (__attribute__((address_space(3))) void*)((char*)Bs + (wid*4 + i)*1024), 16, 0, 0);
    }
    VM0(); BAR();
    #pragma unroll
    for (int kk = 0; kk < 2; ++kk){
      #pragma unroll
      for (int m = 0; m < 4; ++m){
        const int ar = wr*64 + m*16 + (lane & 15);
        const int ssl = (kk*4 + (lane >> 4)) ^ (ar & 7);
        af[m] = *reinterpret_cast<const short8*>(&As[ar*64 + ssl*8]);
      }
      #pragma unroll
      for (int n = 0; n < 4; ++n){
        const int br = wc*64 + n*16 + (lane & 15);
        const int ssl = (kk*4 + (lane >> 4)) ^ (br & 7);
        bf[n] = *reinterpret_cast<const short8*>(&Bs[br*64 + ssl*8]);
      }
      __builtin_amdgcn_s_setprio(1);
      #pragma unroll
      for (int m = 0; m < 4; ++m)
        #pragma unroll
        for (int n = 0; n < 4; ++n)
          acc[m][n] = __builtin_amdgcn_mfma_f32_16x16x32_bf16(af[m], bf[n], acc[m][n], 0, 0, 0);
      __builtin_amdgcn_s_setprio(0);
    }
    BAR();
  }

  // epilogue (C/D layout m89)
  const int which = col0 >> 10;        // 0=Q 1=K 2=V
  const int lcol  = col0 & 1023;
  if (which < 2){
    const float* gate = which ? gk : gq;
    const float* bias = which ? bk : bq;
    const float* ctxv = which ? ck : cq;
    unsigned short* outb = which ? ok : oq;
    unsigned short* tp = (unsigned short*)lds;          // [128][136]
    float* gl = (float*)((char*)lds + 34816);
    float* bl = gl + 128;
    float* cl = bl + 128;
    const int b = row0 >> 11;
    __syncthreads();
    if (t < 128){
      gl[t] = gate[row0 + t];
      bl[t] = bias[lcol + t];
      cl[t] = ctxv[b * H + lcol + t];
    }
    __syncthreads();
    #pragma unroll
    for (int m = 0; m < 4; ++m)
      #pragma unroll
      for (int r = 0; r < 4; ++r){
        const int lr = wr*64 + m*16 + (lane >> 4)*4 + r;
        const float g = gl[lr];
        #pragma unroll
        for (int n = 0; n < 4; ++n){
          const int lc = wc*64 + n*16 + (lane & 15);
          const float q = acc[m][n][r] + bl[lc];
          tp[lr*136 + lc] = f2bf((1.f - g) * q + g * cl[lc]);
        }
      }
    __syncthreads();
    const int rr = t & 127;
    const int cc = (t >> 7) * 64;
    const unsigned short* srcp = tp + rr*136 + cc;
    unsigned short* dst = outb + (size_t)(row0 + rr) * H + lcol + cc;
    #pragma unroll
    for (int i = 0; i < 64; i += 8)
      *reinterpret_cast<ushort8*>(dst + i) = *reinterpret_cast<const ushort8*>(srcp + i);
  } else {
    unsigned short* tp = (unsigned short*)lds;   // [128 h][136 s]
    const int bb = row0 >> 11;
    const int s0 = row0 & (S - 1);
    __syncthreads();
    #pragma unroll
    for (int m = 0; m < 4; ++m)
      #pragma unroll
      for (int r = 0; r < 4; ++r){
        const int lr = wr*64 + m*16 + (lane >> 4)*4 + r;      // s local
        #pragma unroll
        for (int n = 0; n < 4; ++n){
          const int lc = wc*64 + n*16 + (lane & 15);          // h local
          tp[lc*136 + lr] = f2bf(acc[m][n][r] + bv[lcol + lc]);
        }
      }
    __syncthreads();
    const int hh = t & 127;
    const int sc = (t >> 7) * 64;
    const unsigned short* srcp = tp + hh*136 + sc;
    unsigned short* vout = ov + (size_t)bb * H * S + (size_t)(lcol + hh) * S + (size_t)(s0 + sc);
    #pragma unroll
    for (int i = 0; i < 64; i += 8)
      *reinterpret_cast<ushort8*>(vout + i) = *reinterpret_cast<const ushort8*>(srcp + i);
  }
}

// ---------------- 256x256 GEMM (R2 single-barrier schedule) — scores & PV ----------------
#define STG(bufi, opi, halfi, koff, P0, P1) \
  do { __builtin_amdgcn_global_load_lds((const __attribute__((address_space(1))) void*)(P0 + (koff)), \
      (__attribute__((address_space(3))) void*)((char*)(&lds[bufi][opi][halfi][0]) + (wid*2+0)*1024), 16, 0, 0); \
    __builtin_amdgcn_global_load_lds((const __attribute__((address_space(1))) void*)(P1 + (koff)), \
      (__attribute__((address_space(3))) void*)((char*)(&lds[bufi][opi][halfi][0]) + (wid*2+1)*1024), 16, 0, 0); } while(0)
#define STG_A(bufi, halfi, koff) STG(bufi, 0, halfi, koff, sA0, sA1)
#define STG_B(bufi, halfi, koff) STG(bufi, 1, halfi, koff, sB0, sB1)

#define DS_A(bufi, ks, mh) \
  do { _Pragma("unroll") for (int m_ = 0; m_ < 4; ++m_){ \
      const int ar_ = wr*128 + ((mh)*4 + m_)*16 + (lane & 15); \
      const int sl_ = (lane >> 4) ^ ((ar_ >> 1) & 3); \
      af[m_] = *reinterpret_cast<const short8*>(&lds[bufi][0][ks][ar_*32 + sl_*8]); } } while(0)
#define DS_B(bufi, ks) \
  do { _Pragma("unroll") for (int n_ = 0; n_ < 4; ++n_){ \
      const int br_ = wc*64 + n_*16 + (lane & 15); \
      const int sl_ = (lane >> 4) ^ ((br_ >> 1) & 3); \
      bf[n_] = *reinterpret_cast<const short8*>(&lds[bufi][1][ks][br_*32 + sl_*8]); } } while(0)
#define MFMA16(mh) \
  do { __builtin_amdgcn_s_setprio(1); \
    _Pragma("unroll") for (int m_ = 0; m_ < 4; ++m_) \
      _Pragma("unroll") for (int n_ = 0; n_ < 4; ++n_) \
        acc[(mh)*4 + m_][n_] = __builtin_amdgcn_mfma_f32_16x16x32_bf16(af[m_], bf[n_], acc[(mh)*4 + m_][n_], 0, 0, 0); \
    __builtin_amdgcn_s_setprio(0); } while(0)

template<int MODE>
__global__ __launch_bounds__(512, 2)
void k_gemm256(const unsigned short* __restrict__ A, const unsigned short* __restrict__ B,
            int K, int ldA, int ldB, long long Abatch, long long Bbatch,
            unsigned short* __restrict__ oq,
            float* __restrict__ outf, long long outBatch, float scale, float* __restrict__ rsum)
{
  __shared__ __align__(16) short lds[2][2][2][8192];

  const int t = threadIdx.x;
  const int wid = t >> 6, lane = t & 63;
  const int wr = wid >> 2, wc = wid & 3;
  const int bz = blockIdx.z;
  const unsigned short* Ab = A + (size_t)bz * (size_t)Abatch;
  const unsigned short* Bb = B + (size_t)bz * (size_t)Bbatch;
  const int row0 = blockIdx.x * 256;
  const int col0 = blockIdx.y * 256;

  const int c0 = (wid*2 + 0)*64 + lane;
  const int c1 = (wid*2 + 1)*64 + lane;
  const int r0s = c0 >> 2, r1s = c1 >> 2;
  const int kc0 = (c0 & 3) ^ ((r0s >> 1) & 3);
  const int kc1 = (c1 & 3) ^ ((r1s >> 1) & 3);
  const unsigned short* sA0 = Ab + (size_t)(row0 + r0s) * (size_t)ldA + kc0*8;
  const unsigned short* sA1 = Ab + (size_t)(row0 + r1s) * (size_t)ldA + kc1*8;
  const unsigned short* sB0 = Bb + (size_t)(col0 + r0s) * (size_t)ldB + kc0*8;
  const unsigned short* sB1 = Bb + (size_t)(col0 + r1s) * (size_t)ldB + kc1*8;

  f32x4 acc[8][4] = {};
  short8 af[4], bf[4];

  STG_A(0, 0, 0); STG_B(0, 0, 0); STG_A(0, 1, 32); STG_B(0, 1, 32);
  VM0(); BAR();

  const int niter = K >> 7;
  for (int it = 0; it < niter; ++it){
    const int t1k = (it*2 + 1) << 6;
    const int t2k = (it*2 + 2) << 6;
    const bool more = (it + 1 < niter);
    DS_A(0, 0, 0); DS_B(0, 0); STG_A(1, 0, t1k);      MFMA16(0);                              BAR();
    DS_A(0, 0, 1);             STG_B(1, 0, t1k);      MFMA16(1); VM4();                       BAR();
    DS_A(0, 1, 0); DS_B(0, 1); STG_A(1, 1, t1k + 32); MFMA16(0);                              BAR();
    DS_A(0, 1, 1);             STG_B(1, 1, t1k + 32); MFMA16(1); if (more) { VM4(); } else { VM0(); } BAR();
    DS_A(1, 0, 0); DS_B(1, 0); if (more) { STG_A(0, 0, t2k); }      MFMA16(0);                BAR();
    DS_A(1, 0, 1);             if (more) { STG_B(0, 0, t2k); }      MFMA16(1); if (more) { VM4(); } BAR();
    DS_A(1, 1, 0); DS_B(1, 1); if (more) { STG_A(0, 1, t2k + 32); } MFMA16(0);                BAR();
    DS_A(1, 1, 1);             if (more) { STG_B(0, 1, t2k + 32); } MFMA16(1); if (more) { VM4(); } BAR();
  }

  if constexpr (MODE == 3){
    float* rowacc = (float*)lds;
    __syncthreads();
    if (t < 256) rowacc[t] = 0.f;
    __syncthreads();
    #pragma unroll
    for (int mi = 0; mi < 8; ++mi)
      #pragma unroll
      for (int r = 0; r < 4; ++r){
        const int lr = wr*128 + mi*16 + (lane >> 4)*4 + r;
        const int grow = row0 + lr;
        float psum = 0.f;
        #pragma unroll
        for (int n = 0; n < 4; ++n){
          const int gcol = col0 + wc*64 + n*16 + (lane & 15);
          const float val = acc[mi][n][r] * scale;
          outf[(size_t)bz * (size_t)outBatch + (size_t)grow * S + gcol] = val;
          const float pe = __expf(fminf(val, 80.f));
          const unsigned short pb = f2bf(pe);
          oq[(size_t)bz * (size_t)outBatch + (size_t)grow * S + gcol] = pb;
          psum += bf2f(pb);
        }
        #pragma unroll
        for (int off = 1; off < 16; off <<= 1) psum += __shfl_xor(psum, off);
        if ((lane & 15) == 0) atomicAdd(&rowacc[lr], psum);
      }
    __syncthreads();
    if (t < 256) atomicAdd(&rsum[bz * S + row0 + t], rowacc[t]);
  } else {
    float* rs = (float*)lds;
    __syncthreads();
    if (t < 256) rs[t] = 1.f / fmaxf(rsum[bz * S + row0 + t], 1e-35f);
    __syncthreads();
    #pragma unroll
    for (int mi = 0; mi < 8; ++mi)
      #pragma unroll
      for (int r = 0; r < 4; ++r){
        const int lr = wr*128 + mi*16 + (lane >> 4)*4 + r;
        const float inv = rs[lr];
        #pragma unroll
        for (int n = 0; n < 4; ++n){
          const int gcol = col0 + wc*64 + n*16 + (lane & 15);
          outf[(size_t)bz * (size_t)outBatch + (size_t)(row0 + lr) * H + gcol] = acc[mi][n][r] * inv;
        }
      }
  }
}

// ---------------- launch ----------------
extern "C" void kernel_launch(void* const* d_in, const int* in_sizes, int n_in,
                              void* d_out, int out_size, void* d_ws, size_t ws_size,
                              hipStream_t stream) {
  const float* hs  = (const float*)d_in[0];
  const float* ctx = (const float*)d_in[1];
  const float* Wq  = (const float*)d_in[2];
  const float* bq  = (const float*)d_in[3];
  const float* Wk  = (const float*)d_in[4];
  const float* bk  = (const float*)d_in[5];
  const float* Wv  = (const float*)d_in[6];
  const float* bv  = (const float*)d_in[7];
  const float* Wcq = (const float*)d_in[8];
  const float* Wck = (const float*)d_in[9];
  const float* gqh = (const float*)d_in[10];
  const float* gkh = (const float*)d_in[11];
  const float* gqc = (const float*)d_in[12];
  const float* gkc = (const float*)d_in[13];

  char* ws = (char*)d_ws;    // ~768 MB available
  // probs is [NB,S,S] bf16 = 67,108,864 B — full-size slot (R11 lesson).
  unsigned short* hsb   = (unsigned short*)(ws);                   // 33.5 MB
  unsigned short* qhat  = (unsigned short*)(ws + 33554432);        // 33.5 MB
  unsigned short* khat  = (unsigned short*)(ws + 67108864);        // 33.5 MB
  unsigned short* vt    = (unsigned short*)(ws + 100663296);       // 33.5 MB
  unsigned short* probs = (unsigned short*)(ws + 134217728);       // 67.1 MB  [NB,S,S]
  unsigned short* wqb   = (unsigned short*)(ws + 201326592);       // 2 MB (wqb|wkb|wvb contiguous)
  unsigned short* wkb   = (unsigned short*)(ws + 203423744);       // 2 MB
  unsigned short* wvb   = (unsigned short*)(ws + 205520896);       // 2 MB
  float* up    = (float*)(ws + 207618048);                         // 64 KB
  float* u2    = (float*)(ws + 207683584);                         // 8 KB
  float* ctxq  = (float*)(ws + 207691776);                         // 32 KB
  float* ctxk  = (float*)(ws + 207724544);                         // 32 KB
  float* gq    = (float*)(ws + 207757312);                         // 64 KB
  float* gk    = (float*)(ws + 207822848);                         // 64 KB
  float* scal  = (float*)(ws + 207888384);                         // 256 B
  float* rsum  = (float*)(ws + 207888640);                         // 64 KB

  float* out_attn   = (float*)d_out;                        // [NB,S,H]
  float* out_scores = out_attn + (size_t)MROWS * H;         // [NB,S,S]

  hipMemsetAsync(rsum, 0, MROWS * sizeof(float), stream);

  k_prep<<<3649, 256, 0, stream>>>(Wq, Wk, Wv, Wcq, Wck, ctx, gqh, gkh, bq, bk, gqc, gkc,
      wqb, wkb, wvb, up, ctxq, ctxk, scal);
  k_ucombine<<<8, 256, 0, stream>>>(up, u2);
  k_prepass<<<MROWS / 4, 256, 0, stream>>>(hs, u2, scal, hsb, gq, gk);

  // merged QKV (M=16384, N=3072, K=1024), 128^2 tiles, col-fastest grid for A-panel L2 reuse
  k_gemm128<<<dim3(24, 128, 1), 256, 0, stream>>>(hsb, wqb, 1024, 1024, 1024,
      gq, gk, bq, bk, bv, ctxq, ctxk, qhat, khat, vt);

  // scores + fused exp/probs/rowsum (per batch M=N=2048, K=1024), 256^2 tiles
  k_gemm256<3><<<dim3(8, 8, 8), 512, 0, stream>>>(qhat, khat, 1024, 1024, 1024,
      (long long)S * H, (long long)S * H,
      probs, out_scores, (long long)S * S, 0.03125f, rsum);

  // output = (probs @ V) / rowsum (per batch M=2048, N=1024, K=2048), 256^2 tiles
  k_gemm256<5><<<dim3(8, 4, 8), 512, 0, stream>>>(probs, vt, 2048, 2048, 2048,
      (long long)S * S, (long long)H * S,
      nullptr, out_attn, (long long)S * H, 1.f, rsum);
}